// Round 18
// baseline (442.124 us; speedup 1.0000x reference)
//
#include <hip/hip_runtime.h>
#include <hip/hip_bf16.h>

static constexpr int N = 512;    // state size == feature size
static constexpr int L = 16384;  // sequence length
static constexpr int SQX = 16;   // sq blocks occupy bx < SQX in k_drnd

typedef short s16x8 __attribute__((ext_vector_type(8)));
typedef float f32x4 __attribute__((ext_vector_type(4)));
using bf16 = __hip_bfloat16;

#define GPTR(p) ((const __attribute__((address_space(1))) void*)(p))
#define LPTR(p) ((__attribute__((address_space(3))) void*)(p))
__device__ __forceinline__ void gload16(const void* g, void* l) {
    __builtin_amdgcn_global_load_lds(GPTR(g), LPTR(l), 16, 0, 0);
}

__device__ __forceinline__ void split2(float v, ushort& h, ushort& l) {
    bf16 hb = __float2bfloat16(v);
    h = *reinterpret_cast<ushort*>(&hb);
    bf16 lb = __float2bfloat16(v - __bfloat162float(hb));
    l = *reinterpret_cast<ushort*>(&lb);
}
__device__ __forceinline__ ushort f2h(float v) {
    bf16 hb = __float2bfloat16(v);
    return *reinterpret_cast<ushort*>(&hb);
}
__device__ __forceinline__ float us2f(ushort u) {
    return __bfloat162float(*reinterpret_cast<bf16*>(&u));
}

// ---------------- setup kernels ----------------

__global__ void k_zeroinit(int* zb) { zb[blockIdx.x * 256 + threadIdx.x] = 0; }

// M = A*h (straight) and MT = M^T in one pass
__global__ void k_prep(const float* __restrict__ A, float* __restrict__ M,
                       float* __restrict__ MT, float h) {
    __shared__ float t[32][33];
    int bx = blockIdx.x * 32, by = blockIdx.y * 32;
    int tx = threadIdx.x, ty = threadIdx.y;  // block 32x8
#pragma unroll
    for (int j = 0; j < 32; j += 8) {
        float v = A[(by + ty + j) * N + bx + tx] * h;
        t[ty + j][tx] = v;
        M[(by + ty + j) * N + bx + tx] = v;
    }
    __syncthreads();
#pragma unroll
    for (int j = 0; j < 32; j += 8) MT[(bx + ty + j) * N + by + tx] = t[tx][ty + j];
}

// D0 = 2(M+M^2): Dh/Dl straight, Q0=I+D0 pair straight, DTf/DTh/DTl transposed, BL
__global__ void k_buildDT(const float* __restrict__ M, const float* __restrict__ M2,
                          bf16* __restrict__ Dh, bf16* __restrict__ Dl,
                          bf16* __restrict__ Qh, bf16* __restrict__ Ql,
                          float* __restrict__ DTf, bf16* __restrict__ DTh,
                          bf16* __restrict__ DTl, float* __restrict__ BLm) {
    __shared__ float t[32][33];
    int bx = blockIdx.x * 32, by = blockIdx.y * 32;
    int tx = threadIdx.x, ty = threadIdx.y;
#pragma unroll
    for (int j = 0; j < 32; j += 8) {
        int row = by + ty + j, col = bx + tx;
        size_t off = (size_t)row * N + col;
        float m = M[off], m2 = M2[off];
        float d = 2.0f * (m + m2);
        t[ty + j][tx] = d;
        ushort h, l;
        split2(d, h, l);
        *reinterpret_cast<ushort*>(Dh + off) = h;
        *reinterpret_cast<ushort*>(Dl + off) = l;
        float id = (row == col) ? 1.0f : 0.0f;
        split2(d + id, h, l);
        *reinterpret_cast<ushort*>(Qh + off) = h;
        *reinterpret_cast<ushort*>(Ql + off) = l;
        BLm[off] = id + m + m2;
    }
    __syncthreads();
#pragma unroll
    for (int j = 0; j < 32; j += 8) {
        float v = t[tx][ty + j];
        size_t off = (size_t)(bx + ty + j) * N + by + tx;
        DTf[off] = v;
        ushort h, l;
        split2(v, h, l);
        *reinterpret_cast<ushort*>(DTh + off) = h;
        *reinterpret_cast<ushort*>(DTl + off) = l;
    }
}

// vectorized f32 -> (hi, lo) bf16 split, 4 elems/thread
__global__ void k_split4(const float* __restrict__ in, bf16* __restrict__ hi,
                         bf16* __restrict__ lo, int n4) {
    int i = blockIdx.x * 256 + threadIdx.x;
    if (i >= n4) return;
    float4 v = reinterpret_cast<const float4*>(in)[i];
    ushort ht[4], lt[4];
    split2(v.x, ht[0], lt[0]);
    split2(v.y, ht[1], lt[1]);
    split2(v.z, ht[2], lt[2]);
    split2(v.w, ht[3], lt[3]);
    *reinterpret_cast<ushort4*>(hi + 4 * (size_t)i) = *reinterpret_cast<ushort4*>(ht);
    *reinterpret_cast<ushort4*>(lo + 4 * (size_t)i) = *reinterpret_cast<ushort4*>(lt);
}

// 512x512 f32 transpose
__global__ void k_transpose(const float* __restrict__ in, float* __restrict__ out) {
    __shared__ float t[32][33];
    int bx = blockIdx.x * 32, by = blockIdx.y * 32;
    int tx = threadIdx.x, ty = threadIdx.y;  // block 32x8
#pragma unroll
    for (int j = 0; j < 32; j += 8) t[ty + j][tx] = in[(by + ty + j) * N + bx + tx];
    __syncthreads();
#pragma unroll
    for (int j = 0; j < 32; j += 8) out[(bx + ty + j) * N + by + tx] = t[tx][ty + j];
}

// ---------------- f32 NT GEMM 64x64 + fused bf16-split epilogue (setup only) ----
__global__ __launch_bounds__(256) void k_qsq(
    const float* __restrict__ Asrc, const float* __restrict__ Bmat,
    float* __restrict__ OUT, bf16* __restrict__ Sh, bf16* __restrict__ Sl, float scale) {
    __shared__ float As[32][64];
    __shared__ float Bs[32][64];
    const int tid = threadIdx.x;
    const int brow = blockIdx.x * 64;
    const int bcol = blockIdx.y * 64;
    const int tx = tid & 15, ty = tid >> 4;
    float acc[4][4] = {};

    for (int k0 = 0; k0 < N; k0 += 32) {
#pragma unroll
        for (int q = 0; q < 2; ++q) {
            int idx = tid * 2 + q;
            int row = idx >> 3;
            int kq = (idx & 7) << 2;
            float4 va = *(const float4*)(Asrc + (long)(brow + row) * N + k0 + kq);
            As[kq + 0][row] = va.x; As[kq + 1][row] = va.y;
            As[kq + 2][row] = va.z; As[kq + 3][row] = va.w;
            float4 vb = *(const float4*)(Bmat + (long)(bcol + row) * N + k0 + kq);
            Bs[kq + 0][row] = vb.x; Bs[kq + 1][row] = vb.y;
            Bs[kq + 2][row] = vb.z; Bs[kq + 3][row] = vb.w;
        }
        __syncthreads();
#pragma unroll
        for (int kk = 0; kk < 32; ++kk) {
            float a[4], b[4];
            *(float4*)&a[0] = *(const float4*)&As[kk][ty * 4];
            *(float4*)&b[0] = *(const float4*)&Bs[kk][tx * 4];
#pragma unroll
            for (int i = 0; i < 4; ++i)
#pragma unroll
                for (int j = 0; j < 4; ++j) acc[i][j] = fmaf(a[i], b[j], acc[i][j]);
        }
        __syncthreads();
    }
#pragma unroll
    for (int i = 0; i < 4; ++i) {
        long off = (long)(brow + ty * 4 + i) * N + bcol + tx * 4;
        float4 o = make_float4(acc[i][0] * scale, acc[i][1] * scale,
                               acc[i][2] * scale, acc[i][3] * scale);
        *(float4*)(OUT + off) = o;
        ushort ht[4], lt[4];
        split2(o.x, ht[0], lt[0]); split2(o.y, ht[1], lt[1]);
        split2(o.z, ht[2], lt[2]); split2(o.w, ht[3], lt[3]);
        *reinterpret_cast<ushort4*>(Sh + off) = *reinterpret_cast<ushort4*>(ht);
        *reinterpret_cast<ushort4*>(Sl + off) = *reinterpret_cast<ushort4*>(lt);
    }
}

// ---------------- k_bu: X0 = u @ Bb^T (bf16 out), NM=1, u reg-staged ----------
__global__ __launch_bounds__(256, 3) void k_bu(
    const float* __restrict__ u, const bf16* __restrict__ Bbh,
    bf16* __restrict__ Xoh)
{
    __shared__ char smem[32768];
    const int tid = threadIdx.x;
    const int wave = tid >> 6, lane = tid & 63;
    const int wm = wave >> 1, wn = wave & 1;
    const int rl = lane & 15, rh = lane >> 4;
    const long brow = (long)blockIdx.x * 128;
    const int bcol = blockIdx.y * 128;

    f32x4 acc[4][4];
#pragma unroll
    for (int m = 0; m < 4; ++m)
#pragma unroll
        for (int n = 0; n < 4; ++n) acc[m][n] = (f32x4){0.f, 0.f, 0.f, 0.f};

    const float* aptr[2]; int awoff[2];
    const char* pB[2]; int wb[2];
#pragma unroll
    for (int q = 0; q < 2; ++q) {
        int idx = q * 256 + tid;
        int row = idx >> 2, slot = idx & 3;
        int sp = slot ^ ((row >> 1) & 3);
        aptr[q] = u + (brow + row) * N + slot * 8;
        awoff[q] = row * 64 + sp * 16;
        pB[q] = (const char*)(Bbh + (long)(bcol + row) * N + sp * 8);
        wb[q] = (q * 256 + wave * 64) * 16;
    }

    auto stageA = [&](int t, char* buf) {
#pragma unroll
        for (int q = 0; q < 2; ++q) {
            f32x4 v0 = *reinterpret_cast<const f32x4*>(aptr[q] + t * 32);
            f32x4 v1 = *reinterpret_cast<const f32x4*>(aptr[q] + t * 32 + 4);
            s16x8 h;
            h[0] = (short)f2h(v0[0]); h[1] = (short)f2h(v0[1]);
            h[2] = (short)f2h(v0[2]); h[3] = (short)f2h(v0[3]);
            h[4] = (short)f2h(v1[0]); h[5] = (short)f2h(v1[1]);
            h[6] = (short)f2h(v1[2]); h[7] = (short)f2h(v1[3]);
            *reinterpret_cast<s16x8*>(buf + awoff[q]) = h;
        }
    };
    auto stageB = [&](int t, char* buf) {
#pragma unroll
        for (int q = 0; q < 2; ++q) gload16(pB[q] + t * 64, buf + 8192 + wb[q]);
    };

    stageA(0, smem);
    stageB(0, smem);
    __syncthreads();

    for (int t = 0; t < 16; ++t) {
        const char* base = smem + (t & 1) * 16384;
        s16x8 a[4], b[4];
#pragma unroll
        for (int m = 0; m < 4; ++m) {
            int row = wm * 64 + m * 16 + rl;
            a[m] = *reinterpret_cast<const s16x8*>(base + row * 64 + (rh ^ ((row >> 1) & 3)) * 16);
        }
#pragma unroll
        for (int n = 0; n < 4; ++n) {
            int row = wn * 64 + n * 16 + rl;
            b[n] = *reinterpret_cast<const s16x8*>(base + 8192 + row * 64 + (rh ^ ((row >> 1) & 3)) * 16);
        }
        if (t + 1 < 16) {
            char* nb = smem + ((t + 1) & 1) * 16384;
            stageA(t + 1, nb);
            stageB(t + 1, nb);
        }
#pragma unroll
        for (int m = 0; m < 4; ++m)
#pragma unroll
            for (int n = 0; n < 4; ++n)
                acc[m][n] = __builtin_amdgcn_mfma_f32_16x16x32_bf16(a[m], b[n], acc[m][n], 0, 0, 0);
        __syncthreads();
    }

    float* eld = (float*)smem;
    const int erow = tid >> 2;
    const int ec   = (tid & 3) * 8;
    for (int h = 0; h < 2; ++h) {
        if (wm == h) {
#pragma unroll
            for (int m = 0; m < 4; ++m)
#pragma unroll
                for (int q = 0; q < 4; ++q) {
                    int br = m * 16 + rh * 4 + q;
                    int sw = (br & 7) << 2;
#pragma unroll
                    for (int n = 0; n < 4; ++n) {
                        int col = wn * 64 + n * 16 + rl;
                        eld[br * 128 + (col ^ sw)] = acc[m][n][q];
                    }
                }
        }
        __syncthreads();
        {
            long gi = brow + h * 64 + erow;
            const int sw = (erow & 7) << 2;
            long gb = gi * N + bcol;
#pragma unroll
            for (int s = 0; s < 4; ++s) {
                int c = ec + s * 32;
                f32x4 v0 = *reinterpret_cast<const f32x4*>(&eld[erow * 128 + (c ^ sw)]);
                f32x4 v1 = *reinterpret_cast<const f32x4*>(&eld[erow * 128 + ((c ^ sw) ^ 4)]);
                float r[8];
                *reinterpret_cast<f32x4*>(&r[0]) = v0;
                *reinterpret_cast<f32x4*>(&r[4]) = v1;
                ushort oh[8];
#pragma unroll
                for (int j = 0; j < 8; ++j) oh[j] = f2h(r[j]);
                *reinterpret_cast<int4*>(Xoh + gb + c) = *reinterpret_cast<int4*>(oh);
            }
        }
        __syncthreads();
    }
}

// ---------------- k_fin: y = X_hi @ C_hi^T (f32 out), NM=1 -------------------
__global__ __launch_bounds__(256, 3) void k_fin(
    const bf16* __restrict__ Xh, const bf16* __restrict__ Ch, float* __restrict__ Of)
{
    __shared__ char smem[32768];
    const int tid = threadIdx.x;
    const int wave = tid >> 6, lane = tid & 63;
    const int wm = wave >> 1, wn = wave & 1;
    const int rl = lane & 15, rh = lane >> 4;
    const long brow = (long)blockIdx.x * 128;
    const int bcol = blockIdx.y * 128;

    f32x4 acc[4][4];
#pragma unroll
    for (int m = 0; m < 4; ++m)
#pragma unroll
        for (int n = 0; n < 4; ++n) acc[m][n] = (f32x4){0.f, 0.f, 0.f, 0.f};

    const char* pA[2]; const char* pB[2]; int wb[2];
#pragma unroll
    for (int q = 0; q < 2; ++q) {
        int idx = q * 256 + tid;
        int row = idx >> 2, slot = idx & 3;
        int sp = slot ^ ((row >> 1) & 3);
        pA[q] = (const char*)(Xh + (brow + row) * N + sp * 8);
        pB[q] = (const char*)(Ch + (long)(bcol + row) * N + sp * 8);
        wb[q] = (q * 256 + wave * 64) * 16;
    }

#pragma unroll
    for (int q = 0; q < 2; ++q) {
        gload16(pA[q], smem + 0    + wb[q]);
        gload16(pB[q], smem + 8192 + wb[q]);
    }
    __syncthreads();

    for (int t = 0; t < 16; ++t) {
        const char* base = smem + (t & 1) * 16384;
        s16x8 a[4], b[4];
#pragma unroll
        for (int m = 0; m < 4; ++m) {
            int row = wm * 64 + m * 16 + rl;
            a[m] = *reinterpret_cast<const s16x8*>(base + row * 64 + (rh ^ ((row >> 1) & 3)) * 16);
        }
#pragma unroll
        for (int n = 0; n < 4; ++n) {
            int row = wn * 64 + n * 16 + rl;
            b[n] = *reinterpret_cast<const s16x8*>(base + 8192 + row * 64 + (rh ^ ((row >> 1) & 3)) * 16);
        }
        if (t + 1 < 16) {
            const int kb = (t + 1) * 64;
            char* nb = smem + ((t + 1) & 1) * 16384;
#pragma unroll
            for (int q = 0; q < 2; ++q) {
                gload16(pA[q] + kb, nb + 0    + wb[q]);
                gload16(pB[q] + kb, nb + 8192 + wb[q]);
            }
        }
#pragma unroll
        for (int m = 0; m < 4; ++m)
#pragma unroll
            for (int n = 0; n < 4; ++n)
                acc[m][n] = __builtin_amdgcn_mfma_f32_16x16x32_bf16(a[m], b[n], acc[m][n], 0, 0, 0);
        __syncthreads();
    }

    float* eld = (float*)smem;
    const int erow = tid >> 2;
    const int ec   = (tid & 3) * 8;
    for (int h = 0; h < 2; ++h) {
        if (wm == h) {
#pragma unroll
            for (int m = 0; m < 4; ++m)
#pragma unroll
                for (int q = 0; q < 4; ++q) {
                    int br = m * 16 + rh * 4 + q;
                    int sw = (br & 7) << 2;
#pragma unroll
                    for (int n = 0; n < 4; ++n) {
                        int col = wn * 64 + n * 16 + rl;
                        eld[br * 128 + (col ^ sw)] = acc[m][n][q];
                    }
                }
        }
        __syncthreads();
        {
            long gi = brow + h * 64 + erow;
            const int sw = (erow & 7) << 2;
            long gb = gi * N + bcol;
#pragma unroll
            for (int s = 0; s < 4; ++s) {
                int c = ec + s * 32;
                f32x4 v0 = *reinterpret_cast<const f32x4*>(&eld[erow * 128 + (c ^ sw)]);
                f32x4 v1 = *reinterpret_cast<const f32x4*>(&eld[erow * 128 + ((c ^ sw) ^ 4)]);
                *reinterpret_cast<f32x4*>(Of + gb + c)     = v0;
                *reinterpret_cast<f32x4*>(Of + gb + c + 4) = v1;
            }
        }
        __syncthreads();
    }
}

// ---------------- k_drnd: Q-pair doubling round (r16 structure) ---------------
// bx < SQX: sq blocks: Dnext = D^2 + 2D (bf16x3 hi/lo; also emits Qnext = I+Dnext
// pair). else: Xo[i] = Xi[i] + (Qh+Ql)@Xi[i-s]  — the X[i-s] add rides inside
// the MFMA via Q = I+D split pair (diag d preserved in Ql), deleting the 16MB
// epilogue re-read of X[i-s]. X stored plain bf16.
__global__ __launch_bounds__(256, 3) void k_drnd(
    const bf16* __restrict__ Xih, bf16* __restrict__ Xoh,
    const bf16* __restrict__ Dh, const bf16* __restrict__ Dl,
    const bf16* __restrict__ Qh, const bf16* __restrict__ Ql,
    const bf16* __restrict__ DTh, const bf16* __restrict__ DTl,
    const float* __restrict__ DTf,
    bf16* __restrict__ Dnh, bf16* __restrict__ Dnl,
    bf16* __restrict__ Qnh, bf16* __restrict__ Qnl,
    bf16* __restrict__ DTnh, bf16* __restrict__ DTnl, float* __restrict__ DTfn,
    int shift, int doSq, const bf16* __restrict__ zb)
{
    __shared__ char smem[49152];
    const int tid = threadIdx.x;
    const int wave = tid >> 6, lane = tid & 63;
    const int wm = wave >> 1, wn = wave & 1;
    const int rl = lane & 15, rh = lane >> 4;

    if (blockIdx.x < SQX) {
        // ======== D-squaring path (64 blocks, bf16x3) + Qnext emission ========
        if (!doSq) return;
        int sidx = (int)blockIdx.x * (int)gridDim.y + (int)blockIdx.y;  // 0..63
        const int ti = (sidx >> 3) * 64, tj = (sidx & 7) * 64;

        f32x4 acc[2][2];
#pragma unroll
        for (int m = 0; m < 2; ++m)
#pragma unroll
            for (int n = 0; n < 2; ++n) acc[m][n] = (f32x4){0.f, 0.f, 0.f, 0.f};

        int row = tid >> 2, slot = tid & 3;
        int sp = slot ^ ((row >> 1) & 3);
        const char* pAh = (const char*)(DTh + (size_t)(ti + row) * N + sp * 8);
        const char* pAl = (const char*)(DTl + (size_t)(ti + row) * N + sp * 8);
        const char* pBh = (const char*)(Dh + (size_t)(tj + row) * N + sp * 8);
        const char* pBl = (const char*)(Dl + (size_t)(tj + row) * N + sp * 8);
        const int wb = wave * 1024;

        gload16(pAh, smem + 0     + wb);
        gload16(pAl, smem + 4096  + wb);
        gload16(pBh, smem + 8192  + wb);
        gload16(pBl, smem + 12288 + wb);
        __syncthreads();

        for (int t = 0; t < 16; ++t) {
            const char* base = smem + (t & 1) * 16384;
            s16x8 ah[2], al[2], bh[2], bl[2];
#pragma unroll
            for (int m = 0; m < 2; ++m) {
                int r2 = wm * 32 + m * 16 + rl;
                int off = r2 * 64 + (rh ^ ((r2 >> 1) & 3)) * 16;
                ah[m] = *reinterpret_cast<const s16x8*>(base + off);
                al[m] = *reinterpret_cast<const s16x8*>(base + 4096 + off);
            }
#pragma unroll
            for (int n = 0; n < 2; ++n) {
                int r2 = wn * 32 + n * 16 + rl;
                int off = r2 * 64 + (rh ^ ((r2 >> 1) & 3)) * 16;
                bh[n] = *reinterpret_cast<const s16x8*>(base + 8192 + off);
                bl[n] = *reinterpret_cast<const s16x8*>(base + 12288 + off);
            }
            if (t + 1 < 16) {
                const int kb = (t + 1) * 64;
                char* nb = smem + ((t + 1) & 1) * 16384;
                gload16(pAh + kb, nb + 0     + wb);
                gload16(pAl + kb, nb + 4096  + wb);
                gload16(pBh + kb, nb + 8192  + wb);
                gload16(pBl + kb, nb + 12288 + wb);
            }
#pragma unroll
            for (int m = 0; m < 2; ++m)
#pragma unroll
                for (int n = 0; n < 2; ++n) {
                    acc[m][n] = __builtin_amdgcn_mfma_f32_16x16x32_bf16(ah[m], bh[n], acc[m][n], 0, 0, 0);
                    acc[m][n] = __builtin_amdgcn_mfma_f32_16x16x32_bf16(ah[m], bl[n], acc[m][n], 0, 0, 0);
                    acc[m][n] = __builtin_amdgcn_mfma_f32_16x16x32_bf16(al[m], bh[n], acc[m][n], 0, 0, 0);
                }
            __syncthreads();
        }

#pragma unroll
        for (int m = 0; m < 2; ++m)
#pragma unroll
            for (int n = 0; n < 2; ++n)
#pragma unroll
                for (int q = 0; q < 4; ++q) {
                    int i = ti + wm * 32 + m * 16 + rh * 4 + q;
                    int j = tj + wn * 32 + n * 16 + rl;
                    size_t off = (size_t)i * N + j;
                    float v = acc[m][n][q] + 2.0f * DTf[off];   // (D^2)^T + 2 D^T
                    DTfn[off] = v;
                    ushort h, l;
                    split2(v, h, l);
                    *reinterpret_cast<ushort*>(DTnh + off) = h;
                    *reinterpret_cast<ushort*>(DTnl + off) = l;
                    size_t offT = (size_t)j * N + i;
                    *reinterpret_cast<ushort*>(Dnh + offT) = h;
                    *reinterpret_cast<ushort*>(Dnl + offT) = l;
                    // Qnext = I + Dnext (straight orientation)
                    float qv = v + ((i == j) ? 1.0f : 0.0f);
                    split2(qv, h, l);
                    *reinterpret_cast<ushort*>(Qnh + offT) = h;
                    *reinterpret_cast<ushort*>(Qnl + offT) = l;
                }
        return;
    }

    // big path (rows rotated so GEMM blocks dispatch first)
    int bigbx = (int)blockIdx.x - SQX;
    const int sb = shift >> 7;
    int rowBlk = bigbx + sb;
    bool isCopy = false;
    if (rowBlk >= (L / 128)) { rowBlk -= (L / 128); isCopy = true; }
    const long brow = (long)rowBlk * 128;
    const int bcol = blockIdx.y * 128;

    if (isCopy) {
        // rows fully below shift: Xo = Xi (bf16 copy)
#pragma unroll
        for (int j = 0; j < 8; ++j) {
            int c = j * 256 + tid;
            long off = (brow + (c >> 4)) * N + bcol + (c & 15) * 8;
            *reinterpret_cast<int4*>(Xoh + off) = *reinterpret_cast<const int4*>(Xih + off);
        }
        return;
    }

    f32x4 acc[4][4];
#pragma unroll
    for (int m = 0; m < 4; ++m)
#pragma unroll
        for (int n = 0; n < 4; ++n) acc[m][n] = (f32x4){0.f, 0.f, 0.f, 0.f};

    // LDS buffer: A [0,8K), Qh [8K,16K), Ql [16K,24K); dbuf stride 24576
    const char* pA[2]; const char* pBh[2]; const char* pBl[2]; int wb[2];
#pragma unroll
    for (int q = 0; q < 2; ++q) {
        int idx = q * 256 + tid;
        int row = idx >> 2, slot = idx & 3;
        int sp = slot ^ ((row >> 1) & 3);
        long gra = brow + row - (long)shift;
        pA[q] = (gra >= 0) ? (const char*)(Xih + gra * N + sp * 8)
                           : (const char*)(zb + sp * 8);
        long eb = (long)(bcol + row) * N + sp * 8;
        pBh[q] = (const char*)(Qh + eb);
        pBl[q] = (const char*)(Ql + eb);
        wb[q] = (q * 256 + wave * 64) * 16;
    }

#pragma unroll
    for (int q = 0; q < 2; ++q) {
        gload16(pA[q],  smem + 0     + wb[q]);
        gload16(pBh[q], smem + 8192  + wb[q]);
        gload16(pBl[q], smem + 16384 + wb[q]);
    }
    __syncthreads();

    for (int t = 0; t < 16; ++t) {
        const char* base = smem + (t & 1) * 24576;
        s16x8 a[4], bh[4], bl[4];
#pragma unroll
        for (int m = 0; m < 4; ++m) {
            int row = wm * 64 + m * 16 + rl;
            a[m] = *reinterpret_cast<const s16x8*>(base + row * 64 + (rh ^ ((row >> 1) & 3)) * 16);
        }
#pragma unroll
        for (int n = 0; n < 4; ++n) {
            int row = wn * 64 + n * 16 + rl;
            int off = row * 64 + (rh ^ ((row >> 1) & 3)) * 16;
            bh[n] = *reinterpret_cast<const s16x8*>(base + 8192  + off);
            bl[n] = *reinterpret_cast<const s16x8*>(base + 16384 + off);
        }
        if (t + 1 < 16) {
            const int kb = (t + 1) * 64;
            char* nb = smem + ((t + 1) & 1) * 24576;
#pragma unroll
            for (int q = 0; q < 2; ++q) {
                gload16(pA[q]  + kb, nb + 0     + wb[q]);
                gload16(pBh[q] + kb, nb + 8192  + wb[q]);
                gload16(pBl[q] + kb, nb + 16384 + wb[q]);
            }
        }
#pragma unroll
        for (int m = 0; m < 4; ++m)
#pragma unroll
            for (int n = 0; n < 4; ++n) {
                acc[m][n] = __builtin_amdgcn_mfma_f32_16x16x32_bf16(a[m], bh[n], acc[m][n], 0, 0, 0);
                acc[m][n] = __builtin_amdgcn_mfma_f32_16x16x32_bf16(a[m], bl[n], acc[m][n], 0, 0, 0);
            }
        __syncthreads();
    }

    // vectorized epilogue via LDS retile: out = acc + X[i] only
    float* eld = (float*)smem;
    const int erow = tid >> 2;
    const int ec   = (tid & 3) * 8;
    for (int h = 0; h < 2; ++h) {
        if (wm == h) {
#pragma unroll
            for (int m = 0; m < 4; ++m)
#pragma unroll
                for (int q = 0; q < 4; ++q) {
                    int br = m * 16 + rh * 4 + q;
                    int sw = (br & 7) << 2;
#pragma unroll
                    for (int n = 0; n < 4; ++n) {
                        int col = wn * 64 + n * 16 + rl;
                        eld[br * 128 + (col ^ sw)] = acc[m][n][q];
                    }
                }
        }
        __syncthreads();
        {
            long gi = brow + h * 64 + erow;
            const int sw = (erow & 7) << 2;
            long gb = gi * N + bcol;
#pragma unroll
            for (int s = 0; s < 4; ++s) {
                int c = ec + s * 32;
                f32x4 v0 = *reinterpret_cast<const f32x4*>(&eld[erow * 128 + (c ^ sw)]);
                f32x4 v1 = *reinterpret_cast<const f32x4*>(&eld[erow * 128 + ((c ^ sw) ^ 4)]);
                float r[8];
                *reinterpret_cast<f32x4*>(&r[0]) = v0;
                *reinterpret_cast<f32x4*>(&r[4]) = v1;
                ushort vh[8];
                *reinterpret_cast<int4*>(vh) = *reinterpret_cast<const int4*>(Xih + gb + c);
#pragma unroll
                for (int j = 0; j < 8; ++j) r[j] += us2f(vh[j]);
                ushort oh[8];
#pragma unroll
                for (int j = 0; j < 8; ++j) oh[j] = f2h(r[j]);
                *reinterpret_cast<int4*>(Xoh + gb + c) = *reinterpret_cast<int4*>(oh);
            }
        }
        __syncthreads();
    }
}

// ---------------- launcher ----------------

extern "C" void kernel_launch(void* const* d_in, const int* in_sizes, int n_in,
                              void* d_out, int out_size, void* d_ws, size_t ws_size,
                              hipStream_t stream) {
    (void)in_sizes; (void)n_in; (void)out_size; (void)ws_size;
    const float* A = (const float*)d_in[0];
    const float* B = (const float*)d_in[1];
    const float* C = (const float*)d_in[2];
    const float* u = (const float*)d_in[3];

    const size_t NN = (size_t)N * N;
    const size_t LN = (size_t)L * N;

    // X1 (bf16) lives in d_out (16.8MB of the 33.6MB f32 out buffer)
    bf16* X1h = (bf16*)d_out;

    char* w = (char*)d_ws;
    bf16* X0h = (bf16*)w;      w += LN * 2;
    bf16 *Dh_[2], *Dl_[2], *Qh_[2], *Ql_[2], *DTh_[2], *DTl_[2];
    float* DTf_[2];
    for (int s = 0; s < 2; ++s) {
        Dh_[s]  = (bf16*)w;    w += NN * 2;
        Dl_[s]  = (bf16*)w;    w += NN * 2;
        Qh_[s]  = (bf16*)w;    w += NN * 2;
        Ql_[s]  = (bf16*)w;    w += NN * 2;
        DTh_[s] = (bf16*)w;    w += NN * 2;
        DTl_[s] = (bf16*)w;    w += NN * 2;
        DTf_[s] = (float*)w;   w += NN * 4;
    }
    float* M   = (float*)w;    w += NN * 4;
    float* MT  = (float*)w;    w += NN * 4;
    float* M2  = (float*)w;    w += NN * 4;
    float* BLm = (float*)w;    w += NN * 4;
    float* BT  = (float*)w;    w += NN * 4;
    float* Bbf = (float*)w;    w += NN * 4;
    bf16* Bbh  = (bf16*)w;     w += NN * 2;
    bf16* Bbl  = (bf16*)w;     w += NN * 2;
    bf16* Ch   = (bf16*)w;     w += NN * 2;
    bf16* Cl   = (bf16*)w;     w += NN * 2;
    bf16* zb   = (bf16*)w;     w += 2048;

    const float step = 1.0f / (float)L;

    dim3 b256(256);
    dim3 bT(32, 8), gT(N / 32, N / 32);
    dim3 g64(N / 64, N / 64);
    dim3 gBig(L / 128, N / 128);
    dim3 gRound(SQX + L / 128, N / 128);   // sq blocks first, then 128 big rows
    dim3 gS4n((int)(NN / 4 / 256));

    k_zeroinit<<<2, 256, 0, stream>>>((int*)zb);

    // ---- setup (fused) ----
    k_prep<<<gT, bT, 0, stream>>>(A, M, MT, step * 0.5f);                   // M, M^T
    k_qsq<<<g64, b256, 0, stream>>>(M, MT, M2, Bbh, Bbl, 1.0f);             // M2 = M@M (splits scratch)
    k_buildDT<<<gT, bT, 0, stream>>>(M, M2, Dh_[0], Dl_[0], Qh_[0], Ql_[0],
                                     DTf_[0], DTh_[0], DTl_[0], BLm);       // D_0, Q_0, BL
    k_transpose<<<gT, bT, 0, stream>>>(B, BT);
    k_qsq<<<g64, b256, 0, stream>>>(BLm, BT, Bbf, Bbh, Bbl, step);          // Bb (+ split)
    k_split4<<<gS4n, b256, 0, stream>>>(C, Ch, Cl, (int)(NN / 4));

    // ---- Bu = u @ Bb^T -> X0 (bf16) ----
    k_bu<<<gBig, b256, 0, stream>>>(u, Bbh, X0h);

    // ---- 14 doubling rounds, Q-pair form (sq fused, copies last) ----
    for (int r = 0; r < 14; ++r) {
        int s = r & 1, nx = s ^ 1;
        bf16* Xih = (r & 1) ? X1h : X0h;
        bf16* Xoh = (r & 1) ? X0h : X1h;
        int doSq = (r < 13) ? 1 : 0;
        k_drnd<<<gRound, b256, 0, stream>>>(
            Xih, Xoh, Dh_[s], Dl_[s], Qh_[s], Ql_[s],
            DTh_[s], DTl_[s], DTf_[s],
            Dh_[nx], Dl_[nx], Qh_[nx], Ql_[nx],
            DTh_[nx], DTl_[nx], DTf_[nx], 1 << r, doSq, zb);
    }

    // ---- final: OUT = X0_hi @ C_hi^T (f32, overwrites d_out; X1 dead) ----
    k_fin<<<gBig, b256, 0, stream>>>(X0h, Ch, (float*)d_out);
}

// Round 19
// 384.833 us; speedup vs baseline: 1.1489x; 1.1489x over previous
//
#include <hip/hip_runtime.h>
#include <hip/hip_bf16.h>

static constexpr int N = 512;    // state size == feature size
static constexpr int L = 16384;  // sequence length
static constexpr int SQX = 16;   // sq blocks occupy bx < SQX in k_drnd

typedef short s16x8 __attribute__((ext_vector_type(8)));
typedef float f32x4 __attribute__((ext_vector_type(4)));
using bf16 = __hip_bfloat16;

#define GPTR(p) ((const __attribute__((address_space(1))) void*)(p))
#define LPTR(p) ((__attribute__((address_space(3))) void*)(p))
__device__ __forceinline__ void gload16(const void* g, void* l) {
    __builtin_amdgcn_global_load_lds(GPTR(g), LPTR(l), 16, 0, 0);
}

__device__ __forceinline__ void split2(float v, ushort& h, ushort& l) {
    bf16 hb = __float2bfloat16(v);
    h = *reinterpret_cast<ushort*>(&hb);
    bf16 lb = __float2bfloat16(v - __bfloat162float(hb));
    l = *reinterpret_cast<ushort*>(&lb);
}
__device__ __forceinline__ ushort f2h(float v) {
    bf16 hb = __float2bfloat16(v);
    return *reinterpret_cast<ushort*>(&hb);
}
__device__ __forceinline__ float us2f(ushort u) {
    return __bfloat162float(*reinterpret_cast<bf16*>(&u));
}

// ---------------- setup kernels ----------------

__global__ void k_zeroinit(int* zb) { zb[blockIdx.x * 256 + threadIdx.x] = 0; }

// M = A*h (straight) and MT = M^T in one pass
__global__ void k_prep(const float* __restrict__ A, float* __restrict__ M,
                       float* __restrict__ MT, float h) {
    __shared__ float t[32][33];
    int bx = blockIdx.x * 32, by = blockIdx.y * 32;
    int tx = threadIdx.x, ty = threadIdx.y;  // block 32x8
#pragma unroll
    for (int j = 0; j < 32; j += 8) {
        float v = A[(by + ty + j) * N + bx + tx] * h;
        t[ty + j][tx] = v;
        M[(by + ty + j) * N + bx + tx] = v;
    }
    __syncthreads();
#pragma unroll
    for (int j = 0; j < 32; j += 8) MT[(bx + ty + j) * N + by + tx] = t[tx][ty + j];
}

// D0 = 2(M+M^2): writes Dh/Dl straight, DTf/DTh/DTl transposed, BL straight
__global__ void k_buildDT(const float* __restrict__ M, const float* __restrict__ M2,
                          bf16* __restrict__ Dh, bf16* __restrict__ Dl,
                          float* __restrict__ DTf, bf16* __restrict__ DTh,
                          bf16* __restrict__ DTl, float* __restrict__ BLm) {
    __shared__ float t[32][33];
    int bx = blockIdx.x * 32, by = blockIdx.y * 32;
    int tx = threadIdx.x, ty = threadIdx.y;
#pragma unroll
    for (int j = 0; j < 32; j += 8) {
        int row = by + ty + j, col = bx + tx;
        size_t off = (size_t)row * N + col;
        float m = M[off], m2 = M2[off];
        float d = 2.0f * (m + m2);
        t[ty + j][tx] = d;
        ushort h, l;
        split2(d, h, l);
        *reinterpret_cast<ushort*>(Dh + off) = h;
        *reinterpret_cast<ushort*>(Dl + off) = l;
        BLm[off] = ((row == col) ? 1.0f : 0.0f) + m + m2;
    }
    __syncthreads();
#pragma unroll
    for (int j = 0; j < 32; j += 8) {
        float v = t[tx][ty + j];
        size_t off = (size_t)(bx + ty + j) * N + by + tx;
        DTf[off] = v;
        ushort h, l;
        split2(v, h, l);
        *reinterpret_cast<ushort*>(DTh + off) = h;
        *reinterpret_cast<ushort*>(DTl + off) = l;
    }
}

// vectorized f32 -> (hi, lo) bf16 split, 4 elems/thread
__global__ void k_split4(const float* __restrict__ in, bf16* __restrict__ hi,
                         bf16* __restrict__ lo, int n4) {
    int i = blockIdx.x * 256 + threadIdx.x;
    if (i >= n4) return;
    float4 v = reinterpret_cast<const float4*>(in)[i];
    ushort ht[4], lt[4];
    split2(v.x, ht[0], lt[0]);
    split2(v.y, ht[1], lt[1]);
    split2(v.z, ht[2], lt[2]);
    split2(v.w, ht[3], lt[3]);
    *reinterpret_cast<ushort4*>(hi + 4 * (size_t)i) = *reinterpret_cast<ushort4*>(ht);
    *reinterpret_cast<ushort4*>(lo + 4 * (size_t)i) = *reinterpret_cast<ushort4*>(lt);
}

// 512x512 f32 transpose
__global__ void k_transpose(const float* __restrict__ in, float* __restrict__ out) {
    __shared__ float t[32][33];
    int bx = blockIdx.x * 32, by = blockIdx.y * 32;
    int tx = threadIdx.x, ty = threadIdx.y;  // block 32x8
#pragma unroll
    for (int j = 0; j < 32; j += 8) t[ty + j][tx] = in[(by + ty + j) * N + bx + tx];
    __syncthreads();
#pragma unroll
    for (int j = 0; j < 32; j += 8) out[(bx + ty + j) * N + by + tx] = t[tx][ty + j];
}

// ---------------- f32 NT GEMM 64x64 + fused bf16-split epilogue (setup only) ----
__global__ __launch_bounds__(256) void k_qsq(
    const float* __restrict__ Asrc, const float* __restrict__ Bmat,
    float* __restrict__ OUT, bf16* __restrict__ Sh, bf16* __restrict__ Sl, float scale) {
    __shared__ float As[32][64];
    __shared__ float Bs[32][64];
    const int tid = threadIdx.x;
    const int brow = blockIdx.x * 64;
    const int bcol = blockIdx.y * 64;
    const int tx = tid & 15, ty = tid >> 4;
    float acc[4][4] = {};

    for (int k0 = 0; k0 < N; k0 += 32) {
#pragma unroll
        for (int q = 0; q < 2; ++q) {
            int idx = tid * 2 + q;
            int row = idx >> 3;
            int kq = (idx & 7) << 2;
            float4 va = *(const float4*)(Asrc + (long)(brow + row) * N + k0 + kq);
            As[kq + 0][row] = va.x; As[kq + 1][row] = va.y;
            As[kq + 2][row] = va.z; As[kq + 3][row] = va.w;
            float4 vb = *(const float4*)(Bmat + (long)(bcol + row) * N + k0 + kq);
            Bs[kq + 0][row] = vb.x; Bs[kq + 1][row] = vb.y;
            Bs[kq + 2][row] = vb.z; Bs[kq + 3][row] = vb.w;
        }
        __syncthreads();
#pragma unroll
        for (int kk = 0; kk < 32; ++kk) {
            float a[4], b[4];
            *(float4*)&a[0] = *(const float4*)&As[kk][ty * 4];
            *(float4*)&b[0] = *(const float4*)&Bs[kk][tx * 4];
#pragma unroll
            for (int i = 0; i < 4; ++i)
#pragma unroll
                for (int j = 0; j < 4; ++j) acc[i][j] = fmaf(a[i], b[j], acc[i][j]);
        }
        __syncthreads();
    }
#pragma unroll
    for (int i = 0; i < 4; ++i) {
        long off = (long)(brow + ty * 4 + i) * N + bcol + tx * 4;
        float4 o = make_float4(acc[i][0] * scale, acc[i][1] * scale,
                               acc[i][2] * scale, acc[i][3] * scale);
        *(float4*)(OUT + off) = o;
        ushort ht[4], lt[4];
        split2(o.x, ht[0], lt[0]); split2(o.y, ht[1], lt[1]);
        split2(o.z, ht[2], lt[2]); split2(o.w, ht[3], lt[3]);
        *reinterpret_cast<ushort4*>(Sh + off) = *reinterpret_cast<ushort4*>(ht);
        *reinterpret_cast<ushort4*>(Sl + off) = *reinterpret_cast<ushort4*>(lt);
    }
}

// ---------------- k_bu: X0 = u @ Bb^T (bf16 out), NM=1, u reg-staged ----------
__global__ __launch_bounds__(256, 3) void k_bu(
    const float* __restrict__ u, const bf16* __restrict__ Bbh,
    bf16* __restrict__ Xoh)
{
    __shared__ char smem[32768];
    const int tid = threadIdx.x;
    const int wave = tid >> 6, lane = tid & 63;
    const int wm = wave >> 1, wn = wave & 1;
    const int rl = lane & 15, rh = lane >> 4;
    const long brow = (long)blockIdx.x * 128;
    const int bcol = blockIdx.y * 128;

    f32x4 acc[4][4];
#pragma unroll
    for (int m = 0; m < 4; ++m)
#pragma unroll
        for (int n = 0; n < 4; ++n) acc[m][n] = (f32x4){0.f, 0.f, 0.f, 0.f};

    const float* aptr[2]; int awoff[2];
    const char* pB[2]; int wb[2];
#pragma unroll
    for (int q = 0; q < 2; ++q) {
        int idx = q * 256 + tid;
        int row = idx >> 2, slot = idx & 3;
        int sp = slot ^ ((row >> 1) & 3);
        aptr[q] = u + (brow + row) * N + slot * 8;
        awoff[q] = row * 64 + sp * 16;
        pB[q] = (const char*)(Bbh + (long)(bcol + row) * N + sp * 8);
        wb[q] = (q * 256 + wave * 64) * 16;
    }

    auto stageA = [&](int t, char* buf) {
#pragma unroll
        for (int q = 0; q < 2; ++q) {
            f32x4 v0 = *reinterpret_cast<const f32x4*>(aptr[q] + t * 32);
            f32x4 v1 = *reinterpret_cast<const f32x4*>(aptr[q] + t * 32 + 4);
            s16x8 h;
            h[0] = (short)f2h(v0[0]); h[1] = (short)f2h(v0[1]);
            h[2] = (short)f2h(v0[2]); h[3] = (short)f2h(v0[3]);
            h[4] = (short)f2h(v1[0]); h[5] = (short)f2h(v1[1]);
            h[6] = (short)f2h(v1[2]); h[7] = (short)f2h(v1[3]);
            *reinterpret_cast<s16x8*>(buf + awoff[q]) = h;
        }
    };
    auto stageB = [&](int t, char* buf) {
#pragma unroll
        for (int q = 0; q < 2; ++q) gload16(pB[q] + t * 64, buf + 8192 + wb[q]);
    };

    stageA(0, smem);
    stageB(0, smem);
    __syncthreads();

    for (int t = 0; t < 16; ++t) {
        const char* base = smem + (t & 1) * 16384;
        s16x8 a[4], b[4];
#pragma unroll
        for (int m = 0; m < 4; ++m) {
            int row = wm * 64 + m * 16 + rl;
            a[m] = *reinterpret_cast<const s16x8*>(base + row * 64 + (rh ^ ((row >> 1) & 3)) * 16);
        }
#pragma unroll
        for (int n = 0; n < 4; ++n) {
            int row = wn * 64 + n * 16 + rl;
            b[n] = *reinterpret_cast<const s16x8*>(base + 8192 + row * 64 + (rh ^ ((row >> 1) & 3)) * 16);
        }
        if (t + 1 < 16) {
            char* nb = smem + ((t + 1) & 1) * 16384;
            stageA(t + 1, nb);
            stageB(t + 1, nb);
        }
#pragma unroll
        for (int m = 0; m < 4; ++m)
#pragma unroll
            for (int n = 0; n < 4; ++n)
                acc[m][n] = __builtin_amdgcn_mfma_f32_16x16x32_bf16(a[m], b[n], acc[m][n], 0, 0, 0);
        __syncthreads();
    }

    float* eld = (float*)smem;
    const int erow = tid >> 2;
    const int ec   = (tid & 3) * 8;
    for (int h = 0; h < 2; ++h) {
        if (wm == h) {
#pragma unroll
            for (int m = 0; m < 4; ++m)
#pragma unroll
                for (int q = 0; q < 4; ++q) {
                    int br = m * 16 + rh * 4 + q;
                    int sw = (br & 7) << 2;
#pragma unroll
                    for (int n = 0; n < 4; ++n) {
                        int col = wn * 64 + n * 16 + rl;
                        eld[br * 128 + (col ^ sw)] = acc[m][n][q];
                    }
                }
        }
        __syncthreads();
        {
            long gi = brow + h * 64 + erow;
            const int sw = (erow & 7) << 2;
            long gb = gi * N + bcol;
#pragma unroll
            for (int s = 0; s < 4; ++s) {
                int c = ec + s * 32;
                f32x4 v0 = *reinterpret_cast<const f32x4*>(&eld[erow * 128 + (c ^ sw)]);
                f32x4 v1 = *reinterpret_cast<const f32x4*>(&eld[erow * 128 + ((c ^ sw) ^ 4)]);
                float r[8];
                *reinterpret_cast<f32x4*>(&r[0]) = v0;
                *reinterpret_cast<f32x4*>(&r[4]) = v1;
                ushort oh[8];
#pragma unroll
                for (int j = 0; j < 8; ++j) oh[j] = f2h(r[j]);
                *reinterpret_cast<int4*>(Xoh + gb + c) = *reinterpret_cast<int4*>(oh);
            }
        }
        __syncthreads();
    }
}

// ---------------- k_fin: y = X_hi @ C_hi^T (f32 out), NM=1 -------------------
__global__ __launch_bounds__(256, 3) void k_fin(
    const bf16* __restrict__ Xh, const bf16* __restrict__ Ch, float* __restrict__ Of)
{
    __shared__ char smem[32768];
    const int tid = threadIdx.x;
    const int wave = tid >> 6, lane = tid & 63;
    const int wm = wave >> 1, wn = wave & 1;
    const int rl = lane & 15, rh = lane >> 4;
    const long brow = (long)blockIdx.x * 128;
    const int bcol = blockIdx.y * 128;

    f32x4 acc[4][4];
#pragma unroll
    for (int m = 0; m < 4; ++m)
#pragma unroll
        for (int n = 0; n < 4; ++n) acc[m][n] = (f32x4){0.f, 0.f, 0.f, 0.f};

    const char* pA[2]; const char* pB[2]; int wb[2];
#pragma unroll
    for (int q = 0; q < 2; ++q) {
        int idx = q * 256 + tid;
        int row = idx >> 2, slot = idx & 3;
        int sp = slot ^ ((row >> 1) & 3);
        pA[q] = (const char*)(Xh + (brow + row) * N + sp * 8);
        pB[q] = (const char*)(Ch + (long)(bcol + row) * N + sp * 8);
        wb[q] = (q * 256 + wave * 64) * 16;
    }

#pragma unroll
    for (int q = 0; q < 2; ++q) {
        gload16(pA[q], smem + 0    + wb[q]);
        gload16(pB[q], smem + 8192 + wb[q]);
    }
    __syncthreads();

    for (int t = 0; t < 16; ++t) {
        const char* base = smem + (t & 1) * 16384;
        s16x8 a[4], b[4];
#pragma unroll
        for (int m = 0; m < 4; ++m) {
            int row = wm * 64 + m * 16 + rl;
            a[m] = *reinterpret_cast<const s16x8*>(base + row * 64 + (rh ^ ((row >> 1) & 3)) * 16);
        }
#pragma unroll
        for (int n = 0; n < 4; ++n) {
            int row = wn * 64 + n * 16 + rl;
            b[n] = *reinterpret_cast<const s16x8*>(base + 8192 + row * 64 + (rh ^ ((row >> 1) & 3)) * 16);
        }
        if (t + 1 < 16) {
            const int kb = (t + 1) * 64;
            char* nb = smem + ((t + 1) & 1) * 16384;
#pragma unroll
            for (int q = 0; q < 2; ++q) {
                gload16(pA[q] + kb, nb + 0    + wb[q]);
                gload16(pB[q] + kb, nb + 8192 + wb[q]);
            }
        }
#pragma unroll
        for (int m = 0; m < 4; ++m)
#pragma unroll
            for (int n = 0; n < 4; ++n)
                acc[m][n] = __builtin_amdgcn_mfma_f32_16x16x32_bf16(a[m], b[n], acc[m][n], 0, 0, 0);
        __syncthreads();
    }

    float* eld = (float*)smem;
    const int erow = tid >> 2;
    const int ec   = (tid & 3) * 8;
    for (int h = 0; h < 2; ++h) {
        if (wm == h) {
#pragma unroll
            for (int m = 0; m < 4; ++m)
#pragma unroll
                for (int q = 0; q < 4; ++q) {
                    int br = m * 16 + rh * 4 + q;
                    int sw = (br & 7) << 2;
#pragma unroll
                    for (int n = 0; n < 4; ++n) {
                        int col = wn * 64 + n * 16 + rl;
                        eld[br * 128 + (col ^ sw)] = acc[m][n][q];
                    }
                }
        }
        __syncthreads();
        {
            long gi = brow + h * 64 + erow;
            const int sw = (erow & 7) << 2;
            long gb = gi * N + bcol;
#pragma unroll
            for (int s = 0; s < 4; ++s) {
                int c = ec + s * 32;
                f32x4 v0 = *reinterpret_cast<const f32x4*>(&eld[erow * 128 + (c ^ sw)]);
                f32x4 v1 = *reinterpret_cast<const f32x4*>(&eld[erow * 128 + ((c ^ sw) ^ 4)]);
                *reinterpret_cast<f32x4*>(Of + gb + c)     = v0;
                *reinterpret_cast<f32x4*>(Of + gb + c + 4) = v1;
            }
        }
        __syncthreads();
    }
}

// ---------------- k_drnd: D-form doubling round (r10 structure, X bf16-only) --
// bx < SQX: sq blocks: Dnext = D^2 + 2D (bf16x3 hi/lo, unchanged — D chain
// keeps full precision). else: Xo[i] = Xi[i] + Xi[i-s] + (Xi[i-s] @ D_hi^T),
// X stored as plain bf16 (lo plane dropped: halves X traffic; error ~2^-9/round).
__global__ __launch_bounds__(256, 3) void k_drnd(
    const bf16* __restrict__ Xih, bf16* __restrict__ Xoh,
    const bf16* __restrict__ Dh, const bf16* __restrict__ Dl,
    const bf16* __restrict__ DTh, const bf16* __restrict__ DTl,
    const float* __restrict__ DTf,
    bf16* __restrict__ Dnh, bf16* __restrict__ Dnl,
    bf16* __restrict__ DTnh, bf16* __restrict__ DTnl, float* __restrict__ DTfn,
    int shift, int doSq, const bf16* __restrict__ zb)
{
    __shared__ char smem[32768];
    const int tid = threadIdx.x;
    const int wave = tid >> 6, lane = tid & 63;
    const int wm = wave >> 1, wn = wave & 1;
    const int rl = lane & 15, rh = lane >> 4;

    if (blockIdx.x < SQX) {
        // ======== D-squaring path (64 blocks, bf16x3, unchanged from r10) ========
        if (!doSq) return;
        int sidx = (int)blockIdx.x * (int)gridDim.y + (int)blockIdx.y;  // 0..63
        const int ti = (sidx >> 3) * 64, tj = (sidx & 7) * 64;

        f32x4 acc[2][2];
#pragma unroll
        for (int m = 0; m < 2; ++m)
#pragma unroll
            for (int n = 0; n < 2; ++n) acc[m][n] = (f32x4){0.f, 0.f, 0.f, 0.f};

        int row = tid >> 2, slot = tid & 3;
        int sp = slot ^ ((row >> 1) & 3);
        const char* pAh = (const char*)(DTh + (size_t)(ti + row) * N + sp * 8);
        const char* pAl = (const char*)(DTl + (size_t)(ti + row) * N + sp * 8);
        const char* pBh = (const char*)(Dh + (size_t)(tj + row) * N + sp * 8);
        const char* pBl = (const char*)(Dl + (size_t)(tj + row) * N + sp * 8);
        const int wb = wave * 1024;

        gload16(pAh, smem + 0     + wb);
        gload16(pAl, smem + 4096  + wb);
        gload16(pBh, smem + 8192  + wb);
        gload16(pBl, smem + 12288 + wb);
        __syncthreads();

        for (int t = 0; t < 16; ++t) {
            const char* base = smem + (t & 1) * 16384;
            s16x8 ah[2], al[2], bh[2], bl[2];
#pragma unroll
            for (int m = 0; m < 2; ++m) {
                int r2 = wm * 32 + m * 16 + rl;
                int off = r2 * 64 + (rh ^ ((r2 >> 1) & 3)) * 16;
                ah[m] = *reinterpret_cast<const s16x8*>(base + off);
                al[m] = *reinterpret_cast<const s16x8*>(base + 4096 + off);
            }
#pragma unroll
            for (int n = 0; n < 2; ++n) {
                int r2 = wn * 32 + n * 16 + rl;
                int off = r2 * 64 + (rh ^ ((r2 >> 1) & 3)) * 16;
                bh[n] = *reinterpret_cast<const s16x8*>(base + 8192 + off);
                bl[n] = *reinterpret_cast<const s16x8*>(base + 12288 + off);
            }
            if (t + 1 < 16) {
                const int kb = (t + 1) * 64;
                char* nb = smem + ((t + 1) & 1) * 16384;
                gload16(pAh + kb, nb + 0     + wb);
                gload16(pAl + kb, nb + 4096  + wb);
                gload16(pBh + kb, nb + 8192  + wb);
                gload16(pBl + kb, nb + 12288 + wb);
            }
#pragma unroll
            for (int m = 0; m < 2; ++m)
#pragma unroll
                for (int n = 0; n < 2; ++n) {
                    acc[m][n] = __builtin_amdgcn_mfma_f32_16x16x32_bf16(ah[m], bh[n], acc[m][n], 0, 0, 0);
                    acc[m][n] = __builtin_amdgcn_mfma_f32_16x16x32_bf16(ah[m], bl[n], acc[m][n], 0, 0, 0);
                    acc[m][n] = __builtin_amdgcn_mfma_f32_16x16x32_bf16(al[m], bh[n], acc[m][n], 0, 0, 0);
                }
            __syncthreads();
        }

#pragma unroll
        for (int m = 0; m < 2; ++m)
#pragma unroll
            for (int n = 0; n < 2; ++n)
#pragma unroll
                for (int q = 0; q < 4; ++q) {
                    int i = ti + wm * 32 + m * 16 + rh * 4 + q;
                    int j = tj + wn * 32 + n * 16 + rl;
                    size_t off = (size_t)i * N + j;
                    float v = acc[m][n][q] + 2.0f * DTf[off];   // (D^2)^T + 2 D^T
                    DTfn[off] = v;
                    ushort h, l;
                    split2(v, h, l);
                    *reinterpret_cast<ushort*>(DTnh + off) = h;
                    *reinterpret_cast<ushort*>(DTnl + off) = l;
                    size_t offT = (size_t)j * N + i;
                    *reinterpret_cast<ushort*>(Dnh + offT) = h;
                    *reinterpret_cast<ushort*>(Dnl + offT) = l;
                }
        return;
    }

    // big path (rows rotated so GEMM blocks dispatch first)
    int bigbx = (int)blockIdx.x - SQX;
    const int sb = shift >> 7;
    int rowBlk = bigbx + sb;
    bool isCopy = false;
    if (rowBlk >= (L / 128)) { rowBlk -= (L / 128); isCopy = true; }
    const long brow = (long)rowBlk * 128;
    const int bcol = blockIdx.y * 128;

    if (isCopy) {
        // rows fully below shift: Xo = Xi (bf16 copy, 128x128 elems)
#pragma unroll
        for (int j = 0; j < 8; ++j) {
            int c = j * 256 + tid;
            long off = (brow + (c >> 4)) * N + bcol + (c & 15) * 8;
            *reinterpret_cast<int4*>(Xoh + off) = *reinterpret_cast<const int4*>(Xih + off);
        }
        return;
    }

    f32x4 acc[4][4];
#pragma unroll
    for (int m = 0; m < 4; ++m)
#pragma unroll
        for (int n = 0; n < 4; ++n) acc[m][n] = (f32x4){0.f, 0.f, 0.f, 0.f};

    const char* pA[2]; const char* pB[2]; int wb[2];
#pragma unroll
    for (int q = 0; q < 2; ++q) {
        int idx = q * 256 + tid;
        int row = idx >> 2, slot = idx & 3;
        int sp = slot ^ ((row >> 1) & 3);
        long gra = brow + row - (long)shift;
        pA[q] = (gra >= 0) ? (const char*)(Xih + gra * N + sp * 8)
                           : (const char*)(zb + sp * 8);
        pB[q] = (const char*)(Dh + (long)(bcol + row) * N + sp * 8);
        wb[q] = (q * 256 + wave * 64) * 16;
    }

#pragma unroll
    for (int q = 0; q < 2; ++q) {
        gload16(pA[q], smem + 0    + wb[q]);
        gload16(pB[q], smem + 8192 + wb[q]);
    }
    __syncthreads();

    for (int t = 0; t < 16; ++t) {
        const char* base = smem + (t & 1) * 16384;
        s16x8 a[4], b[4];
#pragma unroll
        for (int m = 0; m < 4; ++m) {
            int row = wm * 64 + m * 16 + rl;
            a[m] = *reinterpret_cast<const s16x8*>(base + row * 64 + (rh ^ ((row >> 1) & 3)) * 16);
        }
#pragma unroll
        for (int n = 0; n < 4; ++n) {
            int row = wn * 64 + n * 16 + rl;
            b[n] = *reinterpret_cast<const s16x8*>(base + 8192 + row * 64 + (rh ^ ((row >> 1) & 3)) * 16);
        }
        if (t + 1 < 16) {
            const int kb = (t + 1) * 64;
            char* nb = smem + ((t + 1) & 1) * 16384;
#pragma unroll
            for (int q = 0; q < 2; ++q) {
                gload16(pA[q] + kb, nb + 0    + wb[q]);
                gload16(pB[q] + kb, nb + 8192 + wb[q]);
            }
        }
#pragma unroll
        for (int m = 0; m < 4; ++m)
#pragma unroll
            for (int n = 0; n < 4; ++n)
                acc[m][n] = __builtin_amdgcn_mfma_f32_16x16x32_bf16(a[m], b[n], acc[m][n], 0, 0, 0);
        __syncthreads();
    }

    // vectorized epilogue via LDS retile (two 64-row halves); X reads/writes hi-only
    float* eld = (float*)smem;
    const int erow = tid >> 2;
    const int ec   = (tid & 3) * 8;
    for (int h = 0; h < 2; ++h) {
        if (wm == h) {
#pragma unroll
            for (int m = 0; m < 4; ++m)
#pragma unroll
                for (int q = 0; q < 4; ++q) {
                    int br = m * 16 + rh * 4 + q;
                    int sw = (br & 7) << 2;
#pragma unroll
                    for (int n = 0; n < 4; ++n) {
                        int col = wn * 64 + n * 16 + rl;
                        eld[br * 128 + (col ^ sw)] = acc[m][n][q];
                    }
                }
        }
        __syncthreads();
        {
            long gi = brow + h * 64 + erow;
            bool hasS = gi >= (long)shift;
            const int sw = (erow & 7) << 2;
            long gb = gi * N + bcol;
            long gs = gb - (long)shift * N;
#pragma unroll
            for (int s = 0; s < 4; ++s) {
                int c = ec + s * 32;
                f32x4 v0 = *reinterpret_cast<const f32x4*>(&eld[erow * 128 + (c ^ sw)]);
                f32x4 v1 = *reinterpret_cast<const f32x4*>(&eld[erow * 128 + ((c ^ sw) ^ 4)]);
                float r[8];
                *reinterpret_cast<f32x4*>(&r[0]) = v0;
                *reinterpret_cast<f32x4*>(&r[4]) = v1;
                ushort vh[8];
                *reinterpret_cast<int4*>(vh) = *reinterpret_cast<const int4*>(Xih + gb + c);
#pragma unroll
                for (int j = 0; j < 8; ++j) r[j] += us2f(vh[j]);
                if (hasS) {
                    *reinterpret_cast<int4*>(vh) = *reinterpret_cast<const int4*>(Xih + gs + c);
#pragma unroll
                    for (int j = 0; j < 8; ++j) r[j] += us2f(vh[j]);
                }
                ushort oh[8];
#pragma unroll
                for (int j = 0; j < 8; ++j) oh[j] = f2h(r[j]);
                *reinterpret_cast<int4*>(Xoh + gb + c) = *reinterpret_cast<int4*>(oh);
            }
        }
        __syncthreads();
    }
}

// ---------------- launcher ----------------

extern "C" void kernel_launch(void* const* d_in, const int* in_sizes, int n_in,
                              void* d_out, int out_size, void* d_ws, size_t ws_size,
                              hipStream_t stream) {
    (void)in_sizes; (void)n_in; (void)out_size; (void)ws_size;
    const float* A = (const float*)d_in[0];
    const float* B = (const float*)d_in[1];
    const float* C = (const float*)d_in[2];
    const float* u = (const float*)d_in[3];

    const size_t NN = (size_t)N * N;
    const size_t LN = (size_t)L * N;

    // X1 (bf16) lives in d_out (16.8MB of the 33.6MB f32 out buffer)
    bf16* X1h = (bf16*)d_out;

    char* w = (char*)d_ws;
    bf16* X0h = (bf16*)w;      w += LN * 2;
    bf16 *Dh_[2], *Dl_[2], *DTh_[2], *DTl_[2];
    float* DTf_[2];
    for (int s = 0; s < 2; ++s) {
        Dh_[s]  = (bf16*)w;    w += NN * 2;
        Dl_[s]  = (bf16*)w;    w += NN * 2;
        DTh_[s] = (bf16*)w;    w += NN * 2;
        DTl_[s] = (bf16*)w;    w += NN * 2;
        DTf_[s] = (float*)w;   w += NN * 4;
    }
    float* M   = (float*)w;    w += NN * 4;
    float* MT  = (float*)w;    w += NN * 4;
    float* M2  = (float*)w;    w += NN * 4;
    float* BLm = (float*)w;    w += NN * 4;
    float* BT  = (float*)w;    w += NN * 4;
    float* Bbf = (float*)w;    w += NN * 4;
    bf16* Bbh  = (bf16*)w;     w += NN * 2;
    bf16* Bbl  = (bf16*)w;     w += NN * 2;
    bf16* Ch   = (bf16*)w;     w += NN * 2;
    bf16* Cl   = (bf16*)w;     w += NN * 2;
    bf16* zb   = (bf16*)w;     w += 2048;

    const float step = 1.0f / (float)L;

    dim3 b256(256);
    dim3 bT(32, 8), gT(N / 32, N / 32);
    dim3 g64(N / 64, N / 64);
    dim3 gBig(L / 128, N / 128);
    dim3 gRound(SQX + L / 128, N / 128);   // sq blocks first, then 128 big rows
    dim3 gS4n((int)(NN / 4 / 256));

    k_zeroinit<<<2, 256, 0, stream>>>((int*)zb);

    // ---- setup (fused) ----
    k_prep<<<gT, bT, 0, stream>>>(A, M, MT, step * 0.5f);                   // M, M^T
    k_qsq<<<g64, b256, 0, stream>>>(M, MT, M2, Bbh, Bbl, 1.0f);             // M2 = M@M (splits scratch)
    k_buildDT<<<gT, bT, 0, stream>>>(M, M2, Dh_[0], Dl_[0],
                                     DTf_[0], DTh_[0], DTl_[0], BLm);       // D_0 both orientations, BL
    k_transpose<<<gT, bT, 0, stream>>>(B, BT);
    k_qsq<<<g64, b256, 0, stream>>>(BLm, BT, Bbf, Bbh, Bbl, step);          // Bb (+ split)
    k_split4<<<gS4n, b256, 0, stream>>>(C, Ch, Cl, (int)(NN / 4));

    // ---- Bu = u @ Bb^T -> X0 (bf16) ----
    k_bu<<<gBig, b256, 0, stream>>>(u, Bbh, X0h);

    // ---- 14 doubling rounds, NM=1 D-form, X bf16-only (sq fused, copies last) ----
    for (int r = 0; r < 14; ++r) {
        int s = r & 1, nx = s ^ 1;
        bf16* Xih = (r & 1) ? X1h : X0h;
        bf16* Xoh = (r & 1) ? X0h : X1h;
        int doSq = (r < 13) ? 1 : 0;
        k_drnd<<<gRound, b256, 0, stream>>>(
            Xih, Xoh, Dh_[s], Dl_[s],
            DTh_[s], DTl_[s], DTf_[s],
            Dh_[nx], Dl_[nx], DTh_[nx], DTl_[nx], DTf_[nx], 1 << r, doSq, zb);
    }

    // ---- final: OUT = X0_hi @ C_hi^T (f32, overwrites d_out; X1 dead) ----
    k_fin<<<gBig, b256, 0, stream>>>(X0h, Ch, (float*)d_out);
}